// Round 2
// baseline (96.621 us; speedup 1.0000x reference)
//
#include <hip/hip_runtime.h>
#include <math.h>

// ---------------------------------------------------------------------------
// Algebraic collapse of the reference (see R0): the entire model reduces to
//   y = c0 + c1*S_AB(a,b) + c2*S_BA(a,b);  out = leaky_relu(y)
// with 7 scalars derived only from the weights. Single fused kernel: every
// block recomputes the constants from the (L2-resident) 32x32 weights, then
// grid-strides over the 524288 batch items. No workspace, one dispatch.
// ---------------------------------------------------------------------------

__device__ __forceinline__ float dot4(float4 a, float4 b) {
    return a.x * b.x + a.y * b.y + a.z * b.z + a.w * b.w;
}

__device__ __forceinline__ float sigmoidf_(float x) {
    return 1.0f / (1.0f + expf(-x));
}

__global__ __launch_bounds__(256) void fused_all(
    const float* __restrict__ Af,  // [n,3]
    const float* __restrict__ Bf,  // [n,2]
    const float* __restrict__ WA, const float* __restrict__ bA,
    const float* __restrict__ WB, const float* __restrict__ bB,
    const float* __restrict__ WiAB, const float* __restrict__ biAB,
    const float* __restrict__ WoAB, const float* __restrict__ boAB,
    const float* __restrict__ WiBA, const float* __restrict__ biBA,
    const float* __restrict__ WoBA, const float* __restrict__ boBA,
    const float* __restrict__ Wf, const float* __restrict__ bf,
    float* __restrict__ out, int n)
{
    // ---- phase 1-3: per-block constant derivation (redundant, L2-hit) ----
    __shared__ float uq[2][32], uk[2][32], cq[2][32], uv[2][32], cv[2][32];
    __shared__ float pp[2][32], rr[2][32];
    __shared__ float cst[7];
    const int t = threadIdx.x;

    if (t < 64) {
        const int side = t >> 5;   // 0 = AB (q from A, kv from B), 1 = BA
        const int e = t & 31;
        const float* Wi  = side ? WiBA : WiAB;
        const float* bi  = side ? biBA : biAB;
        const float* wqv = side ? WB : WA;   // query-token weight vec
        const float* bqv = side ? bB : bA;
        const float* wkv = side ? WA : WB;   // key/value-token weight vec
        const float* bkv = side ? bA : bB;

        const float4* rq = (const float4*)(Wi + e * 32);
        const float4* rk = (const float4*)(Wi + (32 + e) * 32);
        const float4* rv = (const float4*)(Wi + (64 + e) * 32);
        const float4* q4 = (const float4*)wqv;
        const float4* qb = (const float4*)bqv;
        const float4* k4 = (const float4*)wkv;
        const float4* kb = (const float4*)bkv;

        float s_uq = 0.f, s_cq = 0.f, s_uk = 0.f, s_uv = 0.f, s_cv = 0.f;
        #pragma unroll
        for (int d = 0; d < 8; ++d) {
            const float4 wq = rq[d], wk = rk[d], wv = rv[d];
            s_uq += dot4(wq, q4[d]);
            s_cq += dot4(wq, qb[d]);
            s_uk += dot4(wk, k4[d]);
            s_uv += dot4(wv, k4[d]);
            s_cv += dot4(wv, kb[d]);
        }
        uq[side][e] = s_uq; cq[side][e] = s_cq + bi[e];
        uk[side][e] = s_uk; uv[side][e] = s_uv; cv[side][e] = s_cv + bi[64 + e];
    }
    __syncthreads();
    if (t < 64) {
        const int side = t >> 5;
        const int e = t & 31;
        const float* Wo = side ? WoBA : WoAB;
        const float* bo = side ? boBA : boAB;
        const float4* ro = (const float4*)(Wo + e * 32);
        const float4* v4 = (const float4*)uv[side];
        const float4* c4 = (const float4*)cv[side];
        float sp = 0.f, sr = 0.f;
        #pragma unroll
        for (int d = 0; d < 8; ++d) {
            const float4 w = ro[d];
            sp += dot4(w, v4[d]);
            sr += dot4(w, c4[d]);
        }
        pp[side][e] = sp; rr[side][e] = sr + bo[e];
    }
    __syncthreads();
    if (t == 0) {
        float aAB = 0.f, gAB = 0.f, aBA = 0.f, gBA = 0.f;
        float c0 = 0.f, c1 = 0.f, c2 = 0.f;
        #pragma unroll
        for (int d = 0; d < 32; ++d) {
            aAB += uq[0][d] * uk[0][d];
            gAB += cq[0][d] * uk[0][d];
            aBA += uq[1][d] * uk[1][d];
            gBA += cq[1][d] * uk[1][d];
            c1  += Wf[d] * pp[0][d];
            c2  += Wf[d] * pp[1][d];
            c0  += Wf[d] * (rr[0][d] + rr[1][d]);
        }
        const float is = 0.17677669529663688f; // 1/sqrt(32)
        cst[0] = aAB * is; cst[1] = gAB * is;
        cst[2] = aBA * is; cst[3] = gBA * is;
        cst[4] = 0.5f * c0 + bf[0];
        cst[5] = 0.5f * c1;
        cst[6] = 0.5f * c2;
    }
    __syncthreads();

    const float kaAB = cst[0], kgAB = cst[1];
    const float kaBA = cst[2], kgBA = cst[3];
    const float c0 = cst[4], c1 = cst[5], c2 = cst[6];

    // ---- main grid-stride streaming phase ----
    const int stride = gridDim.x * blockDim.x;
    for (int i = blockIdx.x * blockDim.x + t; i < n; i += stride) {
        const float a0 = Af[3 * i + 0];
        const float a1 = Af[3 * i + 1];
        const float a2 = Af[3 * i + 2];
        const float2 bb = *reinterpret_cast<const float2*>(Bf + 2 * i);
        const float b0 = bb.x, b1 = bb.y;

        // S_AB: 3 queries (a_i), 2 keys (b_j); 2-key softmax == sigmoid
        const float dB = b0 - b1;
        const float s0 = b1 + dB * sigmoidf_(dB * (kaAB * a0 + kgAB));
        const float s1 = b1 + dB * sigmoidf_(dB * (kaAB * a1 + kgAB));
        const float s2 = b1 + dB * sigmoidf_(dB * (kaAB * a2 + kgAB));
        const float S_AB = (s0 + s1 + s2) * (1.0f / 3.0f);

        // S_BA: 2 queries (b_j), 3 keys (a_i)
        float S_BA = 0.f;
        #pragma unroll
        for (int j = 0; j < 2; ++j) {
            const float bj = (j == 0) ? b0 : b1;
            const float c = kaBA * bj + kgBA;
            const float l0 = a0 * c, l1 = a1 * c, l2 = a2 * c;
            const float m = fmaxf(l0, fmaxf(l1, l2));
            const float e0 = expf(l0 - m), e1 = expf(l1 - m), e2 = expf(l2 - m);
            S_BA += (e0 * a0 + e1 * a1 + e2 * a2) / (e0 + e1 + e2);
        }
        S_BA *= 0.5f;

        const float y = c0 + c1 * S_AB + c2 * S_BA;
        out[i] = (y >= 0.f) ? y : 0.01f * y;
    }
}

extern "C" void kernel_launch(void* const* d_in, const int* in_sizes, int n_in,
                              void* d_out, int out_size, void* d_ws, size_t ws_size,
                              hipStream_t stream) {
    const float* groupA = (const float*)d_in[0];   // [B,3]
    const float* groupB = (const float*)d_in[1];   // [B,2]
    const float* WA   = (const float*)d_in[2];     // [32,1]
    const float* bA   = (const float*)d_in[3];     // [32]
    const float* WB   = (const float*)d_in[4];
    const float* bB   = (const float*)d_in[5];
    const float* WiAB = (const float*)d_in[6];     // [96,32]
    const float* biAB = (const float*)d_in[7];     // [96]
    const float* WoAB = (const float*)d_in[8];     // [32,32]
    const float* boAB = (const float*)d_in[9];     // [32]
    const float* WiBA = (const float*)d_in[10];
    const float* biBA = (const float*)d_in[11];
    const float* WoBA = (const float*)d_in[12];
    const float* boBA = (const float*)d_in[13];
    const float* Wf   = (const float*)d_in[14];    // [1,32]
    const float* bf   = (const float*)d_in[15];    // [1]

    float* out = (float*)d_out;
    const int n = in_sizes[0] / 3;                 // B = 524288

    const int block = 256;
    const int grid = 1024;                         // 2 items/thread grid-stride
    fused_all<<<grid, block, 0, stream>>>(
        groupA, groupB, WA, bA, WB, bB,
        WiAB, biAB, WoAB, boAB, WiBA, biBA, WoBA, boBA,
        Wf, bf, out, n);
}